// Round 4
// baseline (486.567 us; speedup 1.0000x reference)
//
#include <hip/hip_runtime.h>

typedef float f32x4 __attribute__((ext_vector_type(4)));
typedef short s16x8 __attribute__((ext_vector_type(8)));
typedef unsigned short u16;
typedef u16 u16x4 __attribute__((ext_vector_type(4)));

#define SEQ 2048
#define BATCH 2
#define NH 16
#define DH 128
#define DM 2048
#define MROWS (BATCH * SEQ)  // 4096

// 1/sqrt(128) * log2(e)  (softmax done in exp2 domain)
__device__ constexpr float SCALE2 = 0.12751879523531f;

__device__ __forceinline__ u16 f2bf(float f) {
  unsigned u = __float_as_uint(f);
  u += 0x7fffu + ((u >> 16) & 1u);
  return (u16)(u >> 16);
}
__device__ __forceinline__ float bf2f(u16 b) {
  return __uint_as_float(((unsigned)b) << 16);
}

__device__ __forceinline__ void gld_lds16(const void* g, void* l) {
  __builtin_amdgcn_global_load_lds(
      (const __attribute__((address_space(1))) unsigned int*)g,
      (__attribute__((address_space(3))) unsigned int*)l, 16, 0, 0);
}

// ---------------- cast f32 -> bf16 ----------------------------------------
__global__ __launch_bounds__(256) void cast_kernel(const float* __restrict__ in,
                                                   u16* __restrict__ out, int n4) {
  int i = blockIdx.x * 256 + threadIdx.x;
  if (i >= n4) return;
  float4 v = ((const float4*)in)[i];
  u16x4 o;
  o[0] = f2bf(v.x); o[1] = f2bf(v.y); o[2] = f2bf(v.z); o[3] = f2bf(v.w);
  ((u16x4*)out)[i] = o;
}

// ---------------- GEMM C[m][n] = sum_k A[m][k]*B[n][k]  (bt form) ----------
template <bool F32OUT>
__global__ __launch_bounds__(256) void gemm_bt(const u16* __restrict__ A,
                                               const u16* __restrict__ B,
                                               void* __restrict__ Cv,
                                               int M, int N, int K) {
  __shared__ u16 As[128 * 32];
  __shared__ u16 Bs[128 * 32];
  const int tid = threadIdx.x;
  const int wave = tid >> 6;
  const int lane = tid & 63;
  const int r = lane & 15, g = lane >> 4;

  const int m0 = blockIdx.y * 128;
  const int n0 = blockIdx.x * 128;
  const int wm = (wave >> 1) * 64;
  const int wn = (wave & 1) * 64;

  f32x4 acc[4][4] = {};

  const int row0 = tid >> 2;
  const int col0 = (tid & 3) * 8;
  const u16* ga0 = A + (long)(m0 + row0) * K + col0;
  const u16* ga1 = A + (long)(m0 + 64 + row0) * K + col0;
  const u16* gb0 = B + (long)(n0 + row0) * K + col0;
  const u16* gb1 = B + (long)(n0 + 64 + row0) * K + col0;

  u16* lA0 = &As[wave * 512];
  u16* lA1 = &As[2048 + wave * 512];
  u16* lB0 = &Bs[wave * 512];
  u16* lB1 = &Bs[2048 + wave * 512];

  for (int k0 = 0; k0 < K; k0 += 32) {
    gld_lds16(ga0 + k0, lA0);
    gld_lds16(ga1 + k0, lA1);
    gld_lds16(gb0 + k0, lB0);
    gld_lds16(gb1 + k0, lB1);
    __syncthreads();
    s16x8 af[4], bfr[4];
#pragma unroll
    for (int i = 0; i < 4; i++) {
      af[i]  = *(const s16x8*)&As[(wm + i * 16 + r) * 32 + g * 8];
      bfr[i] = *(const s16x8*)&Bs[(wn + i * 16 + r) * 32 + g * 8];
    }
#pragma unroll
    for (int i = 0; i < 4; i++)
#pragma unroll
      for (int j = 0; j < 4; j++)
        acc[i][j] = __builtin_amdgcn_mfma_f32_16x16x32_bf16(af[i], bfr[j], acc[i][j], 0, 0, 0);
    __syncthreads();
  }

  float* Cf = (float*)Cv;
  u16* Cb = (u16*)Cv;
#pragma unroll
  for (int i = 0; i < 4; i++)
#pragma unroll
    for (int j = 0; j < 4; j++) {
      const int row = m0 + wm + i * 16 + g * 4;
      const int col = n0 + wn + j * 16 + r;
#pragma unroll
      for (int q = 0; q < 4; q++) {
        float v = acc[i][j][q];
        if (F32OUT) Cf[(long)(row + q) * N + col] = v;
        else        Cb[(long)(row + q) * N + col] = f2bf(v);
      }
    }
}

// ---------------- RoPE in-place on Qlin & Klin ------------------------------
__global__ __launch_bounds__(256) void rope_kernel(u16* __restrict__ Q, u16* __restrict__ K,
                                                   const float* __restrict__ cosT,
                                                   const float* __restrict__ sinT) {
  int idx = blockIdx.x * 256 + threadIdx.x;  // bits: d:6 h:4 s:11 b:1
  int d = idx & 63;
  int h = (idx >> 6) & 15;
  int s = (idx >> 10) & 2047;
  int b = idx >> 21;
  float c = cosT[s * DH + d];
  float sn = sinT[s * DH + d];
  long base = ((long)(b * SEQ + s)) * DM + h * DH + d;
  float q1 = bf2f(Q[base]), q2 = bf2f(Q[base + 64]);
  Q[base]      = f2bf(q1 * c - q2 * sn);
  Q[base + 64] = f2bf(q2 * c + q1 * sn);
  float k1 = bf2f(K[base]), k2 = bf2f(K[base + 64]);
  K[base]      = f2bf(k1 * c - k2 * sn);
  K[base + 64] = f2bf(k2 * c + k1 * sn);
}

// ---------------- V transpose: Vlin[(b,s)][h*128+d] -> Vt[b,h,d,s] ---------
__global__ __launch_bounds__(256) void transpose_v(const u16* __restrict__ Vlin,
                                                   u16* __restrict__ Vt) {
  __shared__ u16 tile[64][129];
  int t = threadIdx.x;
  int st = blockIdx.x & 31;
  int h = (blockIdx.x >> 5) & 15;
  int b = blockIdx.x >> 9;
  int s0 = st * 64;
  const u16* src = Vlin + ((long)(b * SEQ + s0)) * DM + h * DH;
#pragma unroll
  for (int rr = 0; rr < 4; rr++) {
    int row = rr * 16 + (t >> 4);
    int col = (t & 15) * 8;
    s16x8 v = *(const s16x8*)&src[(long)row * DM + col];
#pragma unroll
    for (int j = 0; j < 8; j++) tile[row][col + j] = (u16)v[j];
  }
  __syncthreads();
  u16* dst = Vt + ((long)(b * NH + h)) * DH * SEQ + s0;
#pragma unroll
  for (int rr = 0; rr < 4; rr++) {
    int d = rr * 32 + (t >> 3);
    int sc = (t & 7) * 8;
    s16x8 o;
#pragma unroll
    for (int j = 0; j < 8; j++) o[j] = (short)tile[sc + j][d];
    *(s16x8*)&dst[(long)d * SEQ + sc] = o;
  }
}

// ---------------- Flash attention v4: split-K -------------------------------
// Swapped QK^T (lane (r,g) holds S[k][q=r]); mirror-paired strips; 2-way
// strided k-split per strip doubles resident waves (grid 1024 = 4 waves/SIMD).
// Partials: Ohat = O/l (bf16) + m,l (f32); combine kernel merges.

__device__ __forceinline__ void softmax_swapped(
    f32x4 (&s)[4], float& mi, float& li,
    u16 (&pl)[16][64], float (&als)[16],
    int qbase, int k0, int r, int g) {
  const int q = qbase + r;
  const bool edge = (k0 + 63) > qbase;
  float v[16];
#pragma unroll
  for (int kk = 0; kk < 4; kk++)
#pragma unroll
    for (int i = 0; i < 4; i++) {
      float x = s[kk][i] * SCALE2;
      if (edge && (k0 + kk * 16 + g * 4 + i > q)) x = -1e30f;
      v[kk * 4 + i] = x;
    }
  float t8[8], t4[4];
#pragma unroll
  for (int j = 0; j < 8; j++) t8[j] = fmaxf(v[2 * j], v[2 * j + 1]);
#pragma unroll
  for (int j = 0; j < 4; j++) t4[j] = fmaxf(t8[2 * j], t8[2 * j + 1]);
  float mx = fmaxf(fmaxf(t4[0], t4[1]), fmaxf(t4[2], t4[3]));
  mx = fmaxf(mx, __shfl_xor(mx, 16, 64));
  mx = fmaxf(mx, __shfl_xor(mx, 32, 64));
  const float mnew = fmaxf(mi, mx);
  const float a = exp2f(mi - mnew);
  float p[16];
#pragma unroll
  for (int j = 0; j < 16; j++) p[j] = exp2f(v[j] - mnew);
  float s8[8], s4[4];
#pragma unroll
  for (int j = 0; j < 8; j++) s8[j] = p[2 * j] + p[2 * j + 1];
#pragma unroll
  for (int j = 0; j < 4; j++) s4[j] = s8[2 * j] + s8[2 * j + 1];
  float ps = (s4[0] + s4[1]) + (s4[2] + s4[3]);
  ps += __shfl_xor(ps, 16, 64);
  ps += __shfl_xor(ps, 32, 64);
  li = li * a + ps;
  mi = mnew;
  const int sw = (r & 7) << 3;
#pragma unroll
  for (int kk = 0; kk < 4; kk++) {
    u16x4 w;
#pragma unroll
    for (int i = 0; i < 4; i++) w[i] = f2bf(p[kk * 4 + i]);
    *(u16x4*)&pl[r][(kk * 16 + g * 4) ^ sw] = w;
  }
  als[r] = a;
}

template <bool DOA>
__device__ __forceinline__ void attn_tile(
    int kt, int r, int g, int qA, int qB,
    const u16* __restrict__ Kbh, const u16* __restrict__ Vbh,
    const s16x8 (&qfA)[4], const s16x8 (&qfB)[4],
    f32x4 (&oaccA)[8], f32x4 (&oaccB)[8],
    float& miA, float& liA, float& miB, float& liB,
    u16 (&pl)[2][16][64], float (&als)[2][16]) {
  const long k0 = (long)kt * 64;
  f32x4 sA[4] = {};
  f32x4 sB[4] = {};
  __builtin_amdgcn_s_setprio(1);
#pragma unroll
  for (int kk = 0; kk < 4; kk++) {
#pragma unroll
    for (int j = 0; j < 4; j++) {
      s16x8 kf = *(const s16x8*)&Kbh[(k0 + kk * 16 + r) * DM + j * 32 + g * 8];
      // SWAPPED operands: K is the A-fragment, Q the B-fragment.
      sB[kk] = __builtin_amdgcn_mfma_f32_16x16x32_bf16(kf, qfB[j], sB[kk], 0, 0, 0);
      if (DOA)
        sA[kk] = __builtin_amdgcn_mfma_f32_16x16x32_bf16(kf, qfA[j], sA[kk], 0, 0, 0);
    }
  }
  __builtin_amdgcn_s_setprio(0);
  softmax_swapped(sB, miB, liB, pl[1], als[1], qB, (int)k0, r, g);
  if (DOA) softmax_swapped(sA, miA, liA, pl[0], als[0], qA, (int)k0, r, g);

  // redistribute alpha to the oacc layout (q = g*4+i) and rescale
  f32x4 avB = *(const f32x4*)&als[1][g * 4];
#pragma unroll
  for (int f = 0; f < 8; f++)
#pragma unroll
    for (int i = 0; i < 4; i++) oaccB[f][i] *= avB[i];
  if (DOA) {
    f32x4 avA = *(const f32x4*)&als[0][g * 4];
#pragma unroll
    for (int f = 0; f < 8; f++)
#pragma unroll
      for (int i = 0; i < 4; i++) oaccA[f][i] *= avA[i];
  }

  const int sw = (r & 7) << 3;
  __builtin_amdgcn_s_setprio(1);
#pragma unroll
  for (int kc = 0; kc < 2; kc++) {
    s16x8 pfB = *(const s16x8*)&pl[1][r][(kc * 32 + g * 8) ^ sw];
    s16x8 pfA = {};
    if (DOA) pfA = *(const s16x8*)&pl[0][r][(kc * 32 + g * 8) ^ sw];
#pragma unroll
    for (int f = 0; f < 8; f++) {
      s16x8 vf = *(const s16x8*)&Vbh[(long)(f * 16 + r) * SEQ + k0 + kc * 32 + g * 8];
      oaccB[f] = __builtin_amdgcn_mfma_f32_16x16x32_bf16(pfB, vf, oaccB[f], 0, 0, 0);
      if (DOA)
        oaccA[f] = __builtin_amdgcn_mfma_f32_16x16x32_bf16(pfA, vf, oaccA[f], 0, 0, 0);
    }
  }
  __builtin_amdgcn_s_setprio(0);
}

// write one strip's partial: Ohat = oacc/l (bf16), m & l (f32)
__device__ __forceinline__ void write_partial(
    u16* __restrict__ OPb, float* __restrict__ ML,
    int sid, int split, float mi, float li,
    f32x4 (&oacc)[8], float (&als)[16], int r, int g) {
  als[r] = (li > 0.f) ? 1.f / li : 0.f;
  f32x4 iv = *(const f32x4*)&als[g * 4];
  u16* op = OPb + ((long)sid * 2 + split) * 2048;
#pragma unroll
  for (int f = 0; f < 8; f++)
#pragma unroll
    for (int i = 0; i < 4; i++)
      op[(g * 4 + i) * 128 + f * 16 + r] = f2bf(oacc[f][i] * iv[i]);
  float* ml = ML + (long)sid * 64 + split * 32;
  ml[r] = mi;
  ml[16 + r] = li;
}

__global__ __launch_bounds__(256) void attn_kernel(const u16* __restrict__ Q,
                                                   const u16* __restrict__ K,
                                                   const u16* __restrict__ Vt,
                                                   u16* __restrict__ OPb,
                                                   float* __restrict__ ML) {
  __shared__ u16 Plds[4][2][16][64];
  __shared__ float Alds[4][2][16];
  const int tid = threadIdx.x, wave = tid >> 6, lane = tid & 63;
  const int r = lane & 15, g = lane >> 4;
  // bh fast-varying -> all blocks of one (b,h) land on XCD bh%8 (L2 pin)
  const int bh = blockIdx.x & 31;
  const int jblk = (blockIdx.x >> 5) & 15;
  const int split = blockIdx.x >> 9;  // 0 or 1
  const int h = bh & 15, b = bh >> 4;
  const int job = jblk * 4 + wave;    // 0..63
  const int qA = job * 16;
  const int qB = (127 - job) * 16;

  const u16* Qbh = Q + (long)b * SEQ * DM + h * DH;
  const u16* Kbh = K + (long)b * SEQ * DM + h * DH;
  const u16* Vbh = Vt + ((long)(b * NH + h)) * DH * SEQ;

  s16x8 qfA[4], qfB[4];
#pragma unroll
  for (int j = 0; j < 4; j++) {
    qfA[j] = *(const s16x8*)&Qbh[(long)(qA + r) * DM + j * 32 + g * 8];
    qfB[j] = *(const s16x8*)&Qbh[(long)(qB + r) * DM + j * 32 + g * 8];
  }

  f32x4 oaccA[8] = {};
  f32x4 oaccB[8] = {};
  float miA = -1e30f, liA = 0.f, miB = -1e30f, liB = 0.f;

  const int nkA = (qA + 15) / 64 + 1;
  const int nkB = (qB + 15) / 64 + 1;

  int kt = split;
  for (; kt < nkA; kt += 2)
    attn_tile<true>(kt, r, g, qA, qB, Kbh, Vbh, qfA, qfB,
                    oaccA, oaccB, miA, liA, miB, liB, Plds[wave], Alds[wave]);
  for (; kt < nkB; kt += 2)
    attn_tile<false>(kt, r, g, qA, qB, Kbh, Vbh, qfA, qfB,
                     oaccA, oaccB, miA, liA, miB, liB, Plds[wave], Alds[wave]);

  write_partial(OPb, ML, bh * 128 + job, split, miA, liA, oaccA,
                Alds[wave][0], r, g);
  write_partial(OPb, ML, bh * 128 + (127 - job), split, miB, liB, oaccB,
                Alds[wave][1], r, g);
}

// ---------------- combine: merge the 2 split partials -----------------------
__global__ __launch_bounds__(256) void attn_combine(const u16* __restrict__ OPb,
                                                    const float* __restrict__ ML,
                                                    u16* __restrict__ O) {
  const int s = blockIdx.x;  // strip id 0..4095
  const int bh = s >> 7;
  const int q0 = (s & 127) * 16;
  const int b = bh >> 4, h = bh & 15;
  const int t = threadIdx.x;
  const int row = t >> 4;
  const int c0 = (t & 15) * 8;
  const float* ml = ML + (long)s * 64;
  const float m0 = ml[row],      l0 = ml[16 + row];
  const float m1 = ml[32 + row], l1 = ml[48 + row];
  const float m = fmaxf(m0, m1);
  float w0 = exp2f(m0 - m) * l0;
  float w1 = exp2f(m1 - m) * l1;
  const float inv = 1.f / (w0 + w1);
  w0 *= inv;
  w1 *= inv;
  const u16* p0 = OPb + ((long)s * 2) * 2048 + row * 128 + c0;
  const u16* p1 = p0 + 2048;
  s16x8 a = *(const s16x8*)p0;
  s16x8 c = *(const s16x8*)p1;
  s16x8 o;
#pragma unroll
  for (int j = 0; j < 8; j++)
    o[j] = (short)f2bf(w0 * bf2f((u16)a[j]) + w1 * bf2f((u16)c[j]));
  *(s16x8*)&O[((long)(b * SEQ + q0 + row)) * DM + h * DH + c0] = o;
}

// ---------------- launch ----------------------------------------------------
extern "C" void kernel_launch(void* const* d_in, const int* in_sizes, int n_in,
                              void* d_out, int out_size, void* d_ws, size_t ws_size,
                              hipStream_t stream) {
  const float* x    = (const float*)d_in[0];
  const float* Wq   = (const float*)d_in[1];
  const float* Wk   = (const float*)d_in[2];
  const float* Wv   = (const float*)d_in[3];
  const float* Wo   = (const float*)d_in[4];
  const float* cosT = (const float*)d_in[5];
  const float* sinT = (const float*)d_in[6];
  // d_in[7] = mask: causal, applied analytically.

  if (ws_size < (size_t)134217728) return;  // need 128 MB scratch

  char* ws = (char*)d_ws;
  u16* xb   = (u16*)(ws);
  u16* Wqb  = (u16*)(ws + 16777216);
  u16* Wkb  = (u16*)(ws + 25165824);
  u16* Wvb  = (u16*)(ws + 33554432);
  u16* Wob  = (u16*)(ws + 41943040);
  u16* Qlin = (u16*)(ws + 50331648);
  u16* Klin = (u16*)(ws + 67108864);
  u16* Vlin = (u16*)(ws + 83886080);
  u16* Vt   = (u16*)(ws + 100663296);
  u16* Olin = (u16*)(ws + 117440512);
  // after the V GEMM, xb/Wqb/Wkb/Wvb (offsets 0..41943040) are dead:
  // reuse for attention partials.
  u16*   OPb = (u16*)(ws);              // 4096 strips x 2 splits x 2048 bf16 = 32 MB
  float* ML  = (float*)(ws + 33554432); // 4096 x 64 f32 = 1 MB (inside dead Wvb)

  cast_kernel<<<8192, 256, 0, stream>>>(x, xb, 8388608 / 4);
  cast_kernel<<<4096, 256, 0, stream>>>(Wq, Wqb, 4194304 / 4);
  cast_kernel<<<4096, 256, 0, stream>>>(Wk, Wkb, 4194304 / 4);
  cast_kernel<<<4096, 256, 0, stream>>>(Wv, Wvb, 4194304 / 4);
  cast_kernel<<<4096, 256, 0, stream>>>(Wo, Wob, 4194304 / 4);

  dim3 ggrid(DM / 128, MROWS / 128);
  gemm_bt<false><<<ggrid, 256, 0, stream>>>(xb, Wqb, Qlin, MROWS, DM, DM);
  gemm_bt<false><<<ggrid, 256, 0, stream>>>(xb, Wkb, Klin, MROWS, DM, DM);
  gemm_bt<false><<<ggrid, 256, 0, stream>>>(xb, Wvb, Vlin, MROWS, DM, DM);

  rope_kernel<<<16384, 256, 0, stream>>>(Qlin, Klin, cosT, sinT);
  transpose_v<<<1024, 256, 0, stream>>>(Vlin, Vt);
  attn_kernel<<<1024, 256, 0, stream>>>(Qlin, Klin, Vt, OPb, ML);
  attn_combine<<<4096, 256, 0, stream>>>(OPb, ML, Olin);

  gemm_bt<true><<<ggrid, 256, 0, stream>>>(Olin, Wob, d_out, MROWS, DM, DM);
}

// Round 5
// 346.003 us; speedup vs baseline: 1.4063x; 1.4063x over previous
//
#include <hip/hip_runtime.h>

typedef float f32x4 __attribute__((ext_vector_type(4)));
typedef short s16x8 __attribute__((ext_vector_type(8)));
typedef unsigned short u16;
typedef u16 u16x4 __attribute__((ext_vector_type(4)));

#define SEQ 2048
#define BATCH 2
#define NH 16
#define DH 128
#define DM 2048
#define MROWS (BATCH * SEQ)  // 4096

// 1/sqrt(128) * log2(e)  (softmax done in exp2 domain)
__device__ constexpr float SCALE2 = 0.12751879523531f;

__device__ __forceinline__ u16 f2bf(float f) {
  unsigned u = __float_as_uint(f);
  u += 0x7fffu + ((u >> 16) & 1u);
  return (u16)(u >> 16);
}
__device__ __forceinline__ float bf2f(u16 b) {
  return __uint_as_float(((unsigned)b) << 16);
}

__device__ __forceinline__ void gld_lds16(const void* g, void* l) {
  __builtin_amdgcn_global_load_lds(
      (const __attribute__((address_space(1))) unsigned int*)g,
      (__attribute__((address_space(3))) unsigned int*)l, 16, 0, 0);
}

// ---------------- cast f32 -> bf16 ----------------------------------------
__global__ __launch_bounds__(256) void cast_kernel(const float* __restrict__ in,
                                                   u16* __restrict__ out, int n4) {
  int i = blockIdx.x * 256 + threadIdx.x;
  if (i >= n4) return;
  float4 v = ((const float4*)in)[i];
  u16x4 o;
  o[0] = f2bf(v.x); o[1] = f2bf(v.y); o[2] = f2bf(v.z); o[3] = f2bf(v.w);
  ((u16x4*)out)[i] = o;
}

// ---------------- GEMM C[m][n] = sum_k A[m][k]*B[n][k]  (bt form) ----------
template <bool F32OUT>
__global__ __launch_bounds__(256) void gemm_bt(const u16* __restrict__ A,
                                               const u16* __restrict__ B,
                                               void* __restrict__ Cv,
                                               int M, int N, int K) {
  __shared__ u16 As[128 * 32];
  __shared__ u16 Bs[128 * 32];
  const int tid = threadIdx.x;
  const int wave = tid >> 6;
  const int lane = tid & 63;
  const int r = lane & 15, g = lane >> 4;

  const int m0 = blockIdx.y * 128;
  const int n0 = blockIdx.x * 128;
  const int wm = (wave >> 1) * 64;
  const int wn = (wave & 1) * 64;

  f32x4 acc[4][4] = {};

  const int row0 = tid >> 2;
  const int col0 = (tid & 3) * 8;
  const u16* ga0 = A + (long)(m0 + row0) * K + col0;
  const u16* ga1 = A + (long)(m0 + 64 + row0) * K + col0;
  const u16* gb0 = B + (long)(n0 + row0) * K + col0;
  const u16* gb1 = B + (long)(n0 + 64 + row0) * K + col0;

  u16* lA0 = &As[wave * 512];
  u16* lA1 = &As[2048 + wave * 512];
  u16* lB0 = &Bs[wave * 512];
  u16* lB1 = &Bs[2048 + wave * 512];

  for (int k0 = 0; k0 < K; k0 += 32) {
    gld_lds16(ga0 + k0, lA0);
    gld_lds16(ga1 + k0, lA1);
    gld_lds16(gb0 + k0, lB0);
    gld_lds16(gb1 + k0, lB1);
    __syncthreads();
    s16x8 af[4], bfr[4];
#pragma unroll
    for (int i = 0; i < 4; i++) {
      af[i]  = *(const s16x8*)&As[(wm + i * 16 + r) * 32 + g * 8];
      bfr[i] = *(const s16x8*)&Bs[(wn + i * 16 + r) * 32 + g * 8];
    }
#pragma unroll
    for (int i = 0; i < 4; i++)
#pragma unroll
      for (int j = 0; j < 4; j++)
        acc[i][j] = __builtin_amdgcn_mfma_f32_16x16x32_bf16(af[i], bfr[j], acc[i][j], 0, 0, 0);
    __syncthreads();
  }

  float* Cf = (float*)Cv;
  u16* Cb = (u16*)Cv;
#pragma unroll
  for (int i = 0; i < 4; i++)
#pragma unroll
    for (int j = 0; j < 4; j++) {
      const int row = m0 + wm + i * 16 + g * 4;
      const int col = n0 + wn + j * 16 + r;
#pragma unroll
      for (int q = 0; q < 4; q++) {
        float v = acc[i][j][q];
        if (F32OUT) Cf[(long)(row + q) * N + col] = v;
        else        Cb[(long)(row + q) * N + col] = f2bf(v);
      }
    }
}

// ---------------- RoPE in-place on Qlin & Klin ------------------------------
__global__ __launch_bounds__(256) void rope_kernel(u16* __restrict__ Q, u16* __restrict__ K,
                                                   const float* __restrict__ cosT,
                                                   const float* __restrict__ sinT) {
  int idx = blockIdx.x * 256 + threadIdx.x;  // bits: d:6 h:4 s:11 b:1
  int d = idx & 63;
  int h = (idx >> 6) & 15;
  int s = (idx >> 10) & 2047;
  int b = idx >> 21;
  float c = cosT[s * DH + d];
  float sn = sinT[s * DH + d];
  long base = ((long)(b * SEQ + s)) * DM + h * DH + d;
  float q1 = bf2f(Q[base]), q2 = bf2f(Q[base + 64]);
  Q[base]      = f2bf(q1 * c - q2 * sn);
  Q[base + 64] = f2bf(q2 * c + q1 * sn);
  float k1 = bf2f(K[base]), k2 = bf2f(K[base + 64]);
  K[base]      = f2bf(k1 * c - k2 * sn);
  K[base + 64] = f2bf(k2 * c + k1 * sn);
}

// ---------------- V transpose: Vlin[(b,s)][h*128+d] -> Vt[b,h,d,s] ---------
__global__ __launch_bounds__(256) void transpose_v(const u16* __restrict__ Vlin,
                                                   u16* __restrict__ Vt) {
  __shared__ u16 tile[64][129];
  int t = threadIdx.x;
  int st = blockIdx.x & 31;
  int h = (blockIdx.x >> 5) & 15;
  int b = blockIdx.x >> 9;
  int s0 = st * 64;
  const u16* src = Vlin + ((long)(b * SEQ + s0)) * DM + h * DH;
#pragma unroll
  for (int rr = 0; rr < 4; rr++) {
    int row = rr * 16 + (t >> 4);
    int col = (t & 15) * 8;
    s16x8 v = *(const s16x8*)&src[(long)row * DM + col];
#pragma unroll
    for (int j = 0; j < 8; j++) tile[row][col + j] = (u16)v[j];
  }
  __syncthreads();
  u16* dst = Vt + ((long)(b * NH + h)) * DH * SEQ + s0;
#pragma unroll
  for (int rr = 0; rr < 4; rr++) {
    int d = rr * 32 + (t >> 3);
    int sc = (t & 7) * 8;
    s16x8 o;
#pragma unroll
    for (int j = 0; j < 8; j++) o[j] = (short)tile[sc + j][d];
    *(s16x8*)&dst[(long)d * SEQ + sc] = o;
  }
}

// ---------------- Flash attention v5: block-cooperative LDS staging --------
// 512-thread block owns mirror strip pair (j, 31-j); waves 0-3 -> 16-row
// strips of A, waves 4-7 -> B. K/V tiles staged via global_load_lds with
// XOR-swizzled source addresses (linear LDS dest, swizzled ds_read) so the
// stride-256B fragment reads are ~2-way instead of 16-way bank conflicts.
// Swapped QK^T softmax (lane holds S[k][q=r]) as verified in rounds 3-4.

__device__ __forceinline__ void softmax_swapped(
    f32x4 (&s)[4], float& mi, float& li,
    u16 (&pl)[16][64], float (&als)[16],
    int qbase, int k0, int r, int g) {
  const int q = qbase + r;
  const bool edge = (k0 + 63) > qbase;
  float v[16];
#pragma unroll
  for (int kk = 0; kk < 4; kk++)
#pragma unroll
    for (int i = 0; i < 4; i++) {
      float x = s[kk][i] * SCALE2;
      if (edge && (k0 + kk * 16 + g * 4 + i > q)) x = -1e30f;
      v[kk * 4 + i] = x;
    }
  float t8[8], t4[4];
#pragma unroll
  for (int j = 0; j < 8; j++) t8[j] = fmaxf(v[2 * j], v[2 * j + 1]);
#pragma unroll
  for (int j = 0; j < 4; j++) t4[j] = fmaxf(t8[2 * j], t8[2 * j + 1]);
  float mx = fmaxf(fmaxf(t4[0], t4[1]), fmaxf(t4[2], t4[3]));
  mx = fmaxf(mx, __shfl_xor(mx, 16, 64));
  mx = fmaxf(mx, __shfl_xor(mx, 32, 64));
  const float mnew = fmaxf(mi, mx);
  const float a = exp2f(mi - mnew);
  float p[16];
#pragma unroll
  for (int j = 0; j < 16; j++) p[j] = exp2f(v[j] - mnew);
  float s8[8], s4[4];
#pragma unroll
  for (int j = 0; j < 8; j++) s8[j] = p[2 * j] + p[2 * j + 1];
#pragma unroll
  for (int j = 0; j < 4; j++) s4[j] = s8[2 * j] + s8[2 * j + 1];
  float ps = (s4[0] + s4[1]) + (s4[2] + s4[3]);
  ps += __shfl_xor(ps, 16, 64);
  ps += __shfl_xor(ps, 32, 64);
  li = li * a + ps;
  mi = mnew;
  const int sw = (r & 7) << 3;
#pragma unroll
  for (int kk = 0; kk < 4; kk++) {
    u16x4 w;
#pragma unroll
    for (int i = 0; i < 4; i++) w[i] = f2bf(p[kk * 4 + i]);
    *(u16x4*)&pl[r][(kk * 16 + g * 4) ^ sw] = w;
  }
  als[r] = a;
}

__global__ __launch_bounds__(512, 4) void attn_kernel(const u16* __restrict__ Q,
                                                      const u16* __restrict__ K,
                                                      const u16* __restrict__ Vt,
                                                      u16* __restrict__ O) {
  __shared__ u16 Klds[64 * 128];   // 16 KB, source-swizzled
  __shared__ u16 Vlds[128 * 64];   // 16 KB, source-swizzled
  __shared__ u16 Plds[8][16][64];  // 16 KB
  __shared__ float Alds[8][16];    // 512 B

  const int tid = threadIdx.x, wave = tid >> 6, lane = tid & 63;
  const int r = lane & 15, g = lane >> 4;
  const int bh = blockIdx.x & 31;   // XCD pin: all blocks of (b,h) on bh%8
  const int j = blockIdx.x >> 5;    // strip-pair 0..15
  const int h = bh & 15, b = bh >> 4;
  const bool isB = wave >= 4;
  const int w4 = wave & 3;
  const int strip = isB ? (31 - j) : j;
  const int q0 = strip * 64 + w4 * 16;
  const int nt = 32 - j;            // staged tiles: kt = 0..31-j
  const int lastA = j;              // A-waves compute while kt <= j

  const u16* Qbh = Q + (long)b * SEQ * DM + h * DH;
  const u16* Kbh = K + (long)b * SEQ * DM + h * DH;
  const u16* Vbh = Vt + ((long)(b * NH + h)) * DH * SEQ;

  s16x8 qf[4];
#pragma unroll
  for (int jj = 0; jj < 4; jj++)
    qf[jj] = *(const s16x8*)&Qbh[(long)(q0 + r) * DM + jj * 32 + g * 8];

  f32x4 oacc[8] = {};
  float mi = -1e30f, li = 0.f;

  for (int kt = 0; kt < nt; ++kt) {
    const int k0 = kt * 64;
    __syncthreads();  // previous tile's LDS readers done
    // ---- stage K (64x128) and V^T (128x64) with source-side XOR swizzle ----
#pragma unroll
    for (int c = 0; c < 2; ++c) {
      const int s = c * 512 + tid;
      const int krow = s >> 4;                    // 0..63
      const int kch = (s & 15) ^ (krow & 7);      // 16B chunk within row
      gld_lds16(Kbh + (long)(k0 + krow) * DM + kch * 8,
                &Klds[(c * 512 + wave * 64) * 8]);
      const int vrow = s >> 3;                    // 0..127
      const int vch = (s & 7) ^ (vrow & 7);
      gld_lds16(Vbh + (long)vrow * SEQ + k0 + vch * 8,
                &Vlds[(c * 512 + wave * 64) * 8]);
    }
    __syncthreads();  // vmcnt(0) drained: tile ready

    const bool active = isB || (kt <= lastA);
    if (active) {
      // ---- QK^T (swapped: K as A-operand) ----
      f32x4 sacc[4] = {};
#pragma unroll
      for (int kk = 0; kk < 4; kk++) {
#pragma unroll
        for (int jj = 0; jj < 4; jj++) {
          s16x8 kf = *(const s16x8*)&Klds[(kk * 16 + r) * 128 +
                                          (((jj * 4 + g) ^ (r & 7)) * 8)];
          sacc[kk] = __builtin_amdgcn_mfma_f32_16x16x32_bf16(kf, qf[jj], sacc[kk], 0, 0, 0);
        }
      }
      softmax_swapped(sacc, mi, li, Plds[wave], Alds[wave], q0, k0, r, g);

      f32x4 av = *(const f32x4*)&Alds[wave][g * 4];
#pragma unroll
      for (int f = 0; f < 8; f++)
#pragma unroll
        for (int i = 0; i < 4; i++) oacc[f][i] *= av[i];

      const int sw = (r & 7) << 3;
#pragma unroll
      for (int kc = 0; kc < 2; kc++) {
        s16x8 pf = *(const s16x8*)&Plds[wave][r][(kc * 32 + g * 8) ^ sw];
#pragma unroll
        for (int f = 0; f < 8; f++) {
          s16x8 vf = *(const s16x8*)&Vlds[(f * 16 + r) * 64 +
                                          (((kc * 4 + g) ^ (r & 7)) * 8)];
          oacc[f] = __builtin_amdgcn_mfma_f32_16x16x32_bf16(pf, vf, oacc[f], 0, 0, 0);
        }
      }
    }
  }

  // ---- epilogue: 1/li redistributed via LDS bounce, direct O write ----
  Alds[wave][r] = 1.f / li;
  f32x4 iv = *(const f32x4*)&Alds[wave][g * 4];
  u16* Obh = O + (long)b * SEQ * DM + h * DH;
#pragma unroll
  for (int f = 0; f < 8; f++)
#pragma unroll
    for (int i = 0; i < 4; i++)
      Obh[(long)(q0 + g * 4 + i) * DM + f * 16 + r] = f2bf(oacc[f][i] * iv[i]);
}

// ---------------- launch ----------------------------------------------------
extern "C" void kernel_launch(void* const* d_in, const int* in_sizes, int n_in,
                              void* d_out, int out_size, void* d_ws, size_t ws_size,
                              hipStream_t stream) {
  const float* x    = (const float*)d_in[0];
  const float* Wq   = (const float*)d_in[1];
  const float* Wk   = (const float*)d_in[2];
  const float* Wv   = (const float*)d_in[3];
  const float* Wo   = (const float*)d_in[4];
  const float* cosT = (const float*)d_in[5];
  const float* sinT = (const float*)d_in[6];
  // d_in[7] = mask: causal, applied analytically.

  if (ws_size < (size_t)134217728) return;  // need 128 MB scratch

  char* ws = (char*)d_ws;
  u16* xb   = (u16*)(ws);
  u16* Wqb  = (u16*)(ws + 16777216);
  u16* Wkb  = (u16*)(ws + 25165824);
  u16* Wvb  = (u16*)(ws + 33554432);
  u16* Wob  = (u16*)(ws + 41943040);
  u16* Qlin = (u16*)(ws + 50331648);
  u16* Klin = (u16*)(ws + 67108864);
  u16* Vlin = (u16*)(ws + 83886080);
  u16* Vt   = (u16*)(ws + 100663296);
  u16* Olin = (u16*)(ws + 117440512);

  cast_kernel<<<8192, 256, 0, stream>>>(x, xb, 8388608 / 4);
  cast_kernel<<<4096, 256, 0, stream>>>(Wq, Wqb, 4194304 / 4);
  cast_kernel<<<4096, 256, 0, stream>>>(Wk, Wkb, 4194304 / 4);
  cast_kernel<<<4096, 256, 0, stream>>>(Wv, Wvb, 4194304 / 4);
  cast_kernel<<<4096, 256, 0, stream>>>(Wo, Wob, 4194304 / 4);

  dim3 ggrid(DM / 128, MROWS / 128);
  gemm_bt<false><<<ggrid, 256, 0, stream>>>(xb, Wqb, Qlin, MROWS, DM, DM);
  gemm_bt<false><<<ggrid, 256, 0, stream>>>(xb, Wkb, Klin, MROWS, DM, DM);
  gemm_bt<false><<<ggrid, 256, 0, stream>>>(xb, Wvb, Vlin, MROWS, DM, DM);

  rope_kernel<<<16384, 256, 0, stream>>>(Qlin, Klin, cosT, sinT);
  transpose_v<<<1024, 256, 0, stream>>>(Vlin, Vt);
  attn_kernel<<<512, 512, 0, stream>>>(Qlin, Klin, Vt, Olin);

  gemm_bt<true><<<ggrid, 256, 0, stream>>>(Olin, Wob, d_out, MROWS, DM, DM);
}

// Round 6
// 295.264 us; speedup vs baseline: 1.6479x; 1.1718x over previous
//
#include <hip/hip_runtime.h>

typedef float f32x4 __attribute__((ext_vector_type(4)));
typedef short s16x8 __attribute__((ext_vector_type(8)));
typedef unsigned short u16;
typedef u16 u16x4 __attribute__((ext_vector_type(4)));

#define SEQ 2048
#define BATCH 2
#define NH 16
#define DH 128
#define DM 2048
#define MROWS (BATCH * SEQ)  // 4096

// 1/sqrt(128) * log2(e)  (softmax done in exp2 domain)
__device__ constexpr float SCALE2 = 0.12751879523531f;

__device__ __forceinline__ u16 f2bf(float f) {
  unsigned u = __float_as_uint(f);
  u += 0x7fffu + ((u >> 16) & 1u);
  return (u16)(u >> 16);
}
__device__ __forceinline__ float bf2f(u16 b) {
  return __uint_as_float(((unsigned)b) << 16);
}

__device__ __forceinline__ void gld_lds16(const void* g, void* l) {
  __builtin_amdgcn_global_load_lds(
      (const __attribute__((address_space(1))) unsigned int*)g,
      (__attribute__((address_space(3))) unsigned int*)l, 16, 0, 0);
}

// ---------------- fused cast f32 -> bf16 (x, Wq|Wk|Wv concat, Wo) ----------
__global__ __launch_bounds__(256) void cast_all(const float* __restrict__ x,
                                                const float* __restrict__ Wq,
                                                const float* __restrict__ Wk,
                                                const float* __restrict__ Wv,
                                                const float* __restrict__ Wo,
                                                u16* __restrict__ xb,
                                                u16* __restrict__ Wqkvb,
                                                u16* __restrict__ Wob) {
  long i = (long)blockIdx.x * 256 + threadIdx.x;  // float4-group index
  const float* src;
  u16* dst;
  long off;
  if (i < 2097152)      { src = x;  dst = xb;              off = i; }
  else if (i < 3145728) { src = Wq; dst = Wqkvb;           off = i - 2097152; }
  else if (i < 4194304) { src = Wk; dst = Wqkvb + 4194304; off = i - 3145728; }
  else if (i < 5242880) { src = Wv; dst = Wqkvb + 8388608; off = i - 4194304; }
  else                  { src = Wo; dst = Wob;             off = i - 5242880; }
  float4 v = ((const float4*)src)[off];
  u16x4 o;
  o[0] = f2bf(v.x); o[1] = f2bf(v.y); o[2] = f2bf(v.z); o[3] = f2bf(v.w);
  ((u16x4*)dst)[off] = o;
}

// ---------------- GEMM core (bt form): C[m][n] = sum_k A[m][k]*B[n][k] -----
// 128x128 tile, BK=32, 4 waves (2x2 of 64x64), mfma 16x16x32 bf16.
// 1D grid with bijective XCD swizzle (nwg % 8 == 0 required).

template <bool F32OUT>
__global__ __launch_bounds__(256) void gemm_bt(const u16* __restrict__ A,
                                               const u16* __restrict__ B,
                                               void* __restrict__ Cv,
                                               int M, int N, int K) {
  __shared__ u16 As[128 * 32];
  __shared__ u16 Bs[128 * 32];
  const int tid = threadIdx.x;
  const int wave = tid >> 6;
  const int lane = tid & 63;
  const int r = lane & 15, g = lane >> 4;

  const int mtiles = M >> 7;
  const int nwg = mtiles * (N >> 7);
  const int cpx = nwg >> 3;
  const int bid = blockIdx.x;
  const int swz = (bid & 7) * cpx + (bid >> 3);
  const int m0 = (swz % mtiles) * 128;
  const int n0 = (swz / mtiles) * 128;

  const int wm = (wave >> 1) * 64;
  const int wn = (wave & 1) * 64;

  f32x4 acc[4][4] = {};

  const int row0 = tid >> 2;
  const int col0 = (tid & 3) * 8;
  const u16* ga0 = A + (long)(m0 + row0) * K + col0;
  const u16* ga1 = A + (long)(m0 + 64 + row0) * K + col0;
  const u16* gb0 = B + (long)(n0 + row0) * K + col0;
  const u16* gb1 = B + (long)(n0 + 64 + row0) * K + col0;

  u16* lA0 = &As[wave * 512];
  u16* lA1 = &As[2048 + wave * 512];
  u16* lB0 = &Bs[wave * 512];
  u16* lB1 = &Bs[2048 + wave * 512];

  for (int k0 = 0; k0 < K; k0 += 32) {
    gld_lds16(ga0 + k0, lA0);
    gld_lds16(ga1 + k0, lA1);
    gld_lds16(gb0 + k0, lB0);
    gld_lds16(gb1 + k0, lB1);
    __syncthreads();
    s16x8 af[4], bfr[4];
#pragma unroll
    for (int i = 0; i < 4; i++) {
      af[i]  = *(const s16x8*)&As[(wm + i * 16 + r) * 32 + g * 8];
      bfr[i] = *(const s16x8*)&Bs[(wn + i * 16 + r) * 32 + g * 8];
    }
#pragma unroll
    for (int i = 0; i < 4; i++)
#pragma unroll
      for (int j = 0; j < 4; j++)
        acc[i][j] = __builtin_amdgcn_mfma_f32_16x16x32_bf16(af[i], bfr[j], acc[i][j], 0, 0, 0);
    __syncthreads();
  }

  float* Cf = (float*)Cv;
  u16* Cb = (u16*)Cv;
#pragma unroll
  for (int i = 0; i < 4; i++)
#pragma unroll
    for (int j = 0; j < 4; j++) {
      const int row = m0 + wm + i * 16 + g * 4;
      const int col = n0 + wn + j * 16 + r;
#pragma unroll
      for (int q = 0; q < 4; q++) {
        float v = acc[i][j][q];
        if (F32OUT) Cf[(long)(row + q) * N + col] = v;
        else        Cb[(long)(row + q) * N + col] = f2bf(v);
      }
    }
}

// ---------------- fused QKV GEMM: B = Wqkv [6144][2048], split outputs -----
__global__ __launch_bounds__(256) void gemm_qkv(const u16* __restrict__ A,
                                                const u16* __restrict__ B,
                                                u16* __restrict__ Qo,
                                                u16* __restrict__ Ko,
                                                u16* __restrict__ Vo) {
  __shared__ u16 As[128 * 32];
  __shared__ u16 Bs[128 * 32];
  const int tid = threadIdx.x;
  const int wave = tid >> 6;
  const int lane = tid & 63;
  const int r = lane & 15, g = lane >> 4;

  // nwg = 1536; XCD chunk = 192 blocks = 6 n-tiles x 32 m-tiles
  // -> per-XCD B-panels (6 x 512 KB = 3 MB) are L2-resident.
  const int bid = blockIdx.x;
  const int swz = (bid & 7) * 192 + (bid >> 3);
  const int m0 = (swz & 31) * 128;   // m-tile fast-varying
  const int n0 = (swz >> 5) * 128;   // n in [0, 6144)

  const int wm = (wave >> 1) * 64;
  const int wn = (wave & 1) * 64;

  f32x4 acc[4][4] = {};

  const int row0 = tid >> 2;
  const int col0 = (tid & 3) * 8;
  const u16* ga0 = A + (long)(m0 + row0) * 2048 + col0;
  const u16* ga1 = A + (long)(m0 + 64 + row0) * 2048 + col0;
  const u16* gb0 = B + (long)(n0 + row0) * 2048 + col0;
  const u16* gb1 = B + (long)(n0 + 64 + row0) * 2048 + col0;

  u16* lA0 = &As[wave * 512];
  u16* lA1 = &As[2048 + wave * 512];
  u16* lB0 = &Bs[wave * 512];
  u16* lB1 = &Bs[2048 + wave * 512];

  for (int k0 = 0; k0 < 2048; k0 += 32) {
    gld_lds16(ga0 + k0, lA0);
    gld_lds16(ga1 + k0, lA1);
    gld_lds16(gb0 + k0, lB0);
    gld_lds16(gb1 + k0, lB1);
    __syncthreads();
    s16x8 af[4], bfr[4];
#pragma unroll
    for (int i = 0; i < 4; i++) {
      af[i]  = *(const s16x8*)&As[(wm + i * 16 + r) * 32 + g * 8];
      bfr[i] = *(const s16x8*)&Bs[(wn + i * 16 + r) * 32 + g * 8];
    }
#pragma unroll
    for (int i = 0; i < 4; i++)
#pragma unroll
      for (int j = 0; j < 4; j++)
        acc[i][j] = __builtin_amdgcn_mfma_f32_16x16x32_bf16(af[i], bfr[j], acc[i][j], 0, 0, 0);
    __syncthreads();
  }

  // split C write: n0 selects Q/K/V (tile-aligned: 2048 % 128 == 0)
  u16* Cb = (n0 < 2048) ? Qo : (n0 < 4096 ? Ko : Vo);
  const int nc0 = n0 & 2047;
#pragma unroll
  for (int i = 0; i < 4; i++)
#pragma unroll
    for (int j = 0; j < 4; j++) {
      const int row = m0 + wm + i * 16 + g * 4;
      const int col = nc0 + wn + j * 16 + r;
#pragma unroll
      for (int q = 0; q < 4; q++)
        Cb[(long)(row + q) * 2048 + col] = f2bf(acc[i][j][q]);
    }
}

// ---------------- RoPE in-place on Qlin & Klin ------------------------------
__global__ __launch_bounds__(256) void rope_kernel(u16* __restrict__ Q, u16* __restrict__ K,
                                                   const float* __restrict__ cosT,
                                                   const float* __restrict__ sinT) {
  int idx = blockIdx.x * 256 + threadIdx.x;  // bits: d:6 h:4 s:11 b:1
  int d = idx & 63;
  int h = (idx >> 6) & 15;
  int s = (idx >> 10) & 2047;
  int b = idx >> 21;
  float c = cosT[s * DH + d];
  float sn = sinT[s * DH + d];
  long base = ((long)(b * SEQ + s)) * DM + h * DH + d;
  float q1 = bf2f(Q[base]), q2 = bf2f(Q[base + 64]);
  Q[base]      = f2bf(q1 * c - q2 * sn);
  Q[base + 64] = f2bf(q2 * c + q1 * sn);
  float k1 = bf2f(K[base]), k2 = bf2f(K[base + 64]);
  K[base]      = f2bf(k1 * c - k2 * sn);
  K[base + 64] = f2bf(k2 * c + k1 * sn);
}

// ---------------- V transpose: Vlin[(b,s)][h*128+d] -> Vt[b,h,d,s] ---------
__global__ __launch_bounds__(256) void transpose_v(const u16* __restrict__ Vlin,
                                                   u16* __restrict__ Vt) {
  __shared__ u16 tile[64][129];
  int t = threadIdx.x;
  int st = blockIdx.x & 31;
  int h = (blockIdx.x >> 5) & 15;
  int b = blockIdx.x >> 9;
  int s0 = st * 64;
  const u16* src = Vlin + ((long)(b * SEQ + s0)) * DM + h * DH;
#pragma unroll
  for (int rr = 0; rr < 4; rr++) {
    int row = rr * 16 + (t >> 4);
    int col = (t & 15) * 8;
    s16x8 v = *(const s16x8*)&src[(long)row * DM + col];
#pragma unroll
    for (int j = 0; j < 8; j++) tile[row][col + j] = (u16)v[j];
  }
  __syncthreads();
  u16* dst = Vt + ((long)(b * NH + h)) * DH * SEQ + s0;
#pragma unroll
  for (int rr = 0; rr < 4; rr++) {
    int d = rr * 32 + (t >> 3);
    int sc = (t & 7) * 8;
    s16x8 o;
#pragma unroll
    for (int j = 0; j < 8; j++) o[j] = (short)tile[sc + j][d];
    *(s16x8*)&dst[(long)d * SEQ + sc] = o;
  }
}

// ---------------- Flash attention v5: block-cooperative LDS staging --------
// (unchanged from round 5 — verified at 89 us)

__device__ __forceinline__ void softmax_swapped(
    f32x4 (&s)[4], float& mi, float& li,
    u16 (&pl)[16][64], float (&als)[16],
    int qbase, int k0, int r, int g) {
  const int q = qbase + r;
  const bool edge = (k0 + 63) > qbase;
  float v[16];
#pragma unroll
  for (int kk = 0; kk < 4; kk++)
#pragma unroll
    for (int i = 0; i < 4; i++) {
      float x = s[kk][i] * SCALE2;
      if (edge && (k0 + kk * 16 + g * 4 + i > q)) x = -1e30f;
      v[kk * 4 + i] = x;
    }
  float t8[8], t4[4];
#pragma unroll
  for (int j = 0; j < 8; j++) t8[j] = fmaxf(v[2 * j], v[2 * j + 1]);
#pragma unroll
  for (int j = 0; j < 4; j++) t4[j] = fmaxf(t8[2 * j], t8[2 * j + 1]);
  float mx = fmaxf(fmaxf(t4[0], t4[1]), fmaxf(t4[2], t4[3]));
  mx = fmaxf(mx, __shfl_xor(mx, 16, 64));
  mx = fmaxf(mx, __shfl_xor(mx, 32, 64));
  const float mnew = fmaxf(mi, mx);
  const float a = exp2f(mi - mnew);
  float p[16];
#pragma unroll
  for (int j = 0; j < 16; j++) p[j] = exp2f(v[j] - mnew);
  float s8[8], s4[4];
#pragma unroll
  for (int j = 0; j < 8; j++) s8[j] = p[2 * j] + p[2 * j + 1];
#pragma unroll
  for (int j = 0; j < 4; j++) s4[j] = s8[2 * j] + s8[2 * j + 1];
  float ps = (s4[0] + s4[1]) + (s4[2] + s4[3]);
  ps += __shfl_xor(ps, 16, 64);
  ps += __shfl_xor(ps, 32, 64);
  li = li * a + ps;
  mi = mnew;
  const int sw = (r & 7) << 3;
#pragma unroll
  for (int kk = 0; kk < 4; kk++) {
    u16x4 w;
#pragma unroll
    for (int i = 0; i < 4; i++) w[i] = f2bf(p[kk * 4 + i]);
    *(u16x4*)&pl[r][(kk * 16 + g * 4) ^ sw] = w;
  }
  als[r] = a;
}

__global__ __launch_bounds__(512, 4) void attn_kernel(const u16* __restrict__ Q,
                                                      const u16* __restrict__ K,
                                                      const u16* __restrict__ Vt,
                                                      u16* __restrict__ O) {
  __shared__ u16 Klds[64 * 128];   // 16 KB, source-swizzled
  __shared__ u16 Vlds[128 * 64];   // 16 KB, source-swizzled
  __shared__ u16 Plds[8][16][64];  // 16 KB
  __shared__ float Alds[8][16];    // 512 B

  const int tid = threadIdx.x, wave = tid >> 6, lane = tid & 63;
  const int r = lane & 15, g = lane >> 4;
  const int bh = blockIdx.x & 31;   // XCD pin: all blocks of (b,h) on bh%8
  const int j = blockIdx.x >> 5;    // strip-pair 0..15
  const int h = bh & 15, b = bh >> 4;
  const bool isB = wave >= 4;
  const int w4 = wave & 3;
  const int strip = isB ? (31 - j) : j;
  const int q0 = strip * 64 + w4 * 16;
  const int nt = 32 - j;            // staged tiles: kt = 0..31-j
  const int lastA = j;              // A-waves compute while kt <= j

  const u16* Qbh = Q + (long)b * SEQ * DM + h * DH;
  const u16* Kbh = K + (long)b * SEQ * DM + h * DH;
  const u16* Vbh = Vt + ((long)(b * NH + h)) * DH * SEQ;

  s16x8 qf[4];
#pragma unroll
  for (int jj = 0; jj < 4; jj++)
    qf[jj] = *(const s16x8*)&Qbh[(long)(q0 + r) * DM + jj * 32 + g * 8];

  f32x4 oacc[8] = {};
  float mi = -1e30f, li = 0.f;

  for (int kt = 0; kt < nt; ++kt) {
    const int k0 = kt * 64;
    __syncthreads();  // previous tile's LDS readers done
    // ---- stage K (64x128) and V^T (128x64) with source-side XOR swizzle ----
#pragma unroll
    for (int c = 0; c < 2; ++c) {
      const int s = c * 512 + tid;
      const int krow = s >> 4;                    // 0..63
      const int kch = (s & 15) ^ (krow & 7);      // 16B chunk within row
      gld_lds16(Kbh + (long)(k0 + krow) * DM + kch * 8,
                &Klds[(c * 512 + wave * 64) * 8]);
      const int vrow = s >> 3;                    // 0..127
      const int vch = (s & 7) ^ (vrow & 7);
      gld_lds16(Vbh + (long)vrow * SEQ + k0 + vch * 8,
                &Vlds[(c * 512 + wave * 64) * 8]);
    }
    __syncthreads();  // vmcnt(0) drained: tile ready

    const bool active = isB || (kt <= lastA);
    if (active) {
      // ---- QK^T (swapped: K as A-operand) ----
      f32x4 sacc[4] = {};
#pragma unroll
      for (int kk = 0; kk < 4; kk++) {
#pragma unroll
        for (int jj = 0; jj < 4; jj++) {
          s16x8 kf = *(const s16x8*)&Klds[(kk * 16 + r) * 128 +
                                          (((jj * 4 + g) ^ (r & 7)) * 8)];
          sacc[kk] = __builtin_amdgcn_mfma_f32_16x16x32_bf16(kf, qf[jj], sacc[kk], 0, 0, 0);
        }
      }
      softmax_swapped(sacc, mi, li, Plds[wave], Alds[wave], q0, k0, r, g);

      f32x4 av = *(const f32x4*)&Alds[wave][g * 4];
#pragma unroll
      for (int f = 0; f < 8; f++)
#pragma unroll
        for (int i = 0; i < 4; i++) oacc[f][i] *= av[i];

      const int sw = (r & 7) << 3;
#pragma unroll
      for (int kc = 0; kc < 2; kc++) {
        s16x8 pf = *(const s16x8*)&Plds[wave][r][(kc * 32 + g * 8) ^ sw];
#pragma unroll
        for (int f = 0; f < 8; f++) {
          s16x8 vf = *(const s16x8*)&Vlds[(f * 16 + r) * 64 +
                                          (((kc * 4 + g) ^ (r & 7)) * 8)];
          oacc[f] = __builtin_amdgcn_mfma_f32_16x16x32_bf16(pf, vf, oacc[f], 0, 0, 0);
        }
      }
    }
  }

  // ---- epilogue: 1/li redistributed via LDS bounce, direct O write ----
  Alds[wave][r] = 1.f / li;
  f32x4 iv = *(const f32x4*)&Alds[wave][g * 4];
  u16* Obh = O + (long)b * SEQ * DM + h * DH;
#pragma unroll
  for (int f = 0; f < 8; f++)
#pragma unroll
    for (int i = 0; i < 4; i++)
      Obh[(long)(q0 + g * 4 + i) * DM + f * 16 + r] = f2bf(oacc[f][i] * iv[i]);
}

// ---------------- launch ----------------------------------------------------
extern "C" void kernel_launch(void* const* d_in, const int* in_sizes, int n_in,
                              void* d_out, int out_size, void* d_ws, size_t ws_size,
                              hipStream_t stream) {
  const float* x    = (const float*)d_in[0];
  const float* Wq   = (const float*)d_in[1];
  const float* Wk   = (const float*)d_in[2];
  const float* Wv   = (const float*)d_in[3];
  const float* Wo   = (const float*)d_in[4];
  const float* cosT = (const float*)d_in[5];
  const float* sinT = (const float*)d_in[6];
  // d_in[7] = mask: causal, applied analytically.

  if (ws_size < (size_t)134217728) return;  // need 128 MB scratch

  char* ws = (char*)d_ws;
  u16* xb    = (u16*)(ws);               // 16 MB
  u16* Wqkvb = (u16*)(ws + 16777216);    // 24 MB [Wq;Wk;Wv] rows
  u16* Wob   = (u16*)(ws + 41943040);    //  8 MB
  u16* Qlin  = (u16*)(ws + 50331648);    // 16 MB
  u16* Klin  = (u16*)(ws + 67108864);    // 16 MB
  u16* Vlin  = (u16*)(ws + 83886080);    // 16 MB
  u16* Vt    = (u16*)(ws + 100663296);   // 16 MB
  u16* Olin  = (u16*)(ws + 117440512);   // 16 MB

  cast_all<<<24576, 256, 0, stream>>>(x, Wq, Wk, Wv, Wo, xb, Wqkvb, Wob);

  gemm_qkv<<<1536, 256, 0, stream>>>(xb, Wqkvb, Qlin, Klin, Vlin);

  rope_kernel<<<16384, 256, 0, stream>>>(Qlin, Klin, cosT, sinT);
  transpose_v<<<1024, 256, 0, stream>>>(Vlin, Vt);
  attn_kernel<<<512, 512, 0, stream>>>(Qlin, Klin, Vt, Olin);

  gemm_bt<true><<<512, 256, 0, stream>>>(Olin, Wob, d_out, MROWS, DM, DM);
}